// Round 10
// baseline (411.512 us; speedup 1.0000x reference)
//
#include <hip/hip_runtime.h>

// ResidualVQ: Q=4, N_EMBED=1024, DIM=256, B=8, S=2048 (fp32).
// out = [quantized 8*2048*256][indices-as-float 4*8*2048][losses 4]
//
// R22: R21's split architecture with the staging bug fixed. R21 failed
// because k_pref's resid->LDS load wrote 8 float4/thread (8192 f4 = 128 rows)
// into a 32-row LDS tile — OOB writes smashed sX/sBK/candD -> wrong candidate
// sets -> wrong indices. Correct count: 32 rows x 64 f4 = 2048 f4 = 2/thread.
// Architecture (unchanged from R21): break the monolith's barrier-lockstep
// phase chain (the ~70us/stage floor invariant to spill/occupancy/blocks/
// tile across R13-R20) into homogeneous kernels per stage:
//   k_pref: staging + av + MFMA prefilter + threshold + gather
//   k_rank: rerank + fallback + idx + STE + loss (wave-autonomous, 0 barriers)
// Candidate scratch (candL/cnt/av) lives in the out_q region (free until
// k_final) -> zero ws growth.
// Certified exact re-rank structure FROZEN (R11-R20): bf16-MFMA prefilter,
// tau margin 8x slack, frozen np fp32 distance chain, tie -> lower index,
// frozen STE recursion. Indices/outputs bit-identical to R19's logic.
#define QQ   4
#define NE   1024
#define DIMD 256
#define MM   16384
#define TM   32     // rows per k_pref block
#define NW   16     // waves per k_pref block (1024 threads)
#define CAP  32     // candidate slots per row

typedef short v8s __attribute__((ext_vector_type(8)));   // 8 x bf16
typedef float v4f __attribute__((ext_vector_type(4)));

// ws layout (float offsets) — within the R12-proven footprint:
//  cb16  [QQ][NE][DIMD] ushort @ 0        (524,288 floats)
//  bK    [QQ][NE]              @ 524,288  (4,096)
//  lossP double[QQ][64]        @ 528,384  (512 floats; byte 2,113,536 %8==0)
//  resid [MM][DIMD]            @ 528,896  (4,194,304)
// out-region scratch (free until k_final):
//  candS int[MM][CAP] @ out+0 ; cntS int[MM] @ out+524,288 ; avS @ out+540,672

__device__ __forceinline__ unsigned short f2bf(float f) {  // RNE fp32->bf16
  unsigned u = __float_as_uint(f);
  return (unsigned short)((u + 0x7FFFu + ((u >> 16) & 1u)) >> 16);
}

// FROZEN numpy pairwise sumsq of 256 f32, over a 32-aligned group of 32 lanes
// (j = lane-in-group). Valid on j==0. Identical op tree/pairing as scalar.
__device__ __forceinline__ float np_sumsq_256_x32(const float* __restrict__ p,
                                                  int j) {
  const int bi = j >> 4, L = j & 15;
  const float* q = p + bi * 128 + L;
  float s0 = __fmul_rn(q[0], q[0]);
  float s1 = __fmul_rn(q[16], q[16]);
  float s2 = __fmul_rn(q[32], q[32]);
  float s3 = __fmul_rn(q[48], q[48]);
  float s4 = __fmul_rn(q[64], q[64]);
  float s5 = __fmul_rn(q[80], q[80]);
  float s6 = __fmul_rn(q[96], q[96]);
  float s7 = __fmul_rn(q[112], q[112]);
  float w = __fadd_rn(__fadd_rn(__fadd_rn(s0, s1), __fadd_rn(s2, s3)),
                      __fadd_rn(__fadd_rn(s4, s5), __fadd_rn(s6, s7)));
  float u  = __fadd_rn(w,  __shfl_down(w, 8, 64));   // valid L<8
  float t  = __fadd_rn(u,  __shfl_down(u, 4, 64));   // valid L<4
  float r2 = __fadd_rn(t,  __shfl_down(t, 2, 64));   // valid L<2
  float bb = __fadd_rn(r2, __shfl_down(r2, 1, 64));  // valid L==0 -> blk[bi]
  return __fadd_rn(bb, __shfl_down(bb, 16, 64));     // valid j==0
}

// frozen np distance, float4-load pipelined (IDENTICAL fma sequence/order;
// unroll width is scheduling-only — chain order unchanged)
__device__ __forceinline__ float np_dist_f4(const float* __restrict__ xp,
                                            const float* __restrict__ ep,
                                            float a, float b) {
  float m = 0.f;
  #pragma unroll 8
  for (int d4 = 0; d4 < DIMD / 4; ++d4) {
    const float4 xv = *(const float4*)(xp + d4 * 4);
    const float4 ev = *(const float4*)(ep + d4 * 4);
    m = fmaf(xv.x, ev.x, m);
    m = fmaf(xv.y, ev.y, m);
    m = fmaf(xv.z, ev.z, m);
    m = fmaf(xv.w, ev.w, m);
  }
  return __fadd_rn(__fsub_rn(a, __fmul_rn(2.0f, m)), b);
}

// prep: coalesced LDS staging per 8 codebook rows -> bK (frozen x32 tree) +
// bf16 conversion; plus x->resid copy and lossP zero. 512 blocks x 256 thr.
__global__ __launch_bounds__(256) void k_prep(const float* __restrict__ cb,
                                              const float* __restrict__ x,
                                              unsigned short* __restrict__ cb16,
                                              float* __restrict__ bK,
                                              float* __restrict__ resid,
                                              double* __restrict__ lossP) {
  __shared__ float rowS[8][256];
  const int t = threadIdx.x;
  const size_t base = (size_t)blockIdx.x * 2048;     // 8 rows of 256 floats
  {  // coalesced global->LDS: 512 float4, 2 per thread
    const float4* src = (const float4*)(cb + base);
    float4* dst = (float4*)rowS;
    dst[t] = src[t];
    dst[t + 256] = src[t + 256];
  }
  __syncthreads();
  {  // bK: (row r=t>>5, lane j=t&31), frozen x32 tree on identical bits
    const int r = t >> 5, j = t & 31;
    float b = np_sumsq_256_x32(&rowS[r][0], j);
    if (j == 0) bK[blockIdx.x * 8 + r] = b;
  }
  {  // cb16: 8 elems/thread (RNE), coalesced 16B writes
    const float* p = &((const float*)rowS)[t * 8];
    unsigned short o[8];
    #pragma unroll
    for (int k = 0; k < 8; ++k) o[k] = f2bf(p[k]);
    *(v8s*)(cb16 + base + (size_t)t * 8) = *(v8s*)o;
  }
  {  // x -> resid (exact copy), grid-stride float4
    const float4* xs = (const float4*)x;
    float4* rd = (float4*)resid;
    const int gt = blockIdx.x * 256 + t;             // 131072 threads
    #pragma unroll
    for (int k = 0; k < 8; ++k) rd[gt + k * 131072] = xs[gt + k * 131072];
  }
  if (blockIdx.x == 0) lossP[t] = 0.0;               // 256 doubles exactly
}

// prefilter: 1024 thr = 16 waves, 32 rows/block, 512 blocks.
// Wave w covers codes [w*64,(w+1)*64): 4 col-tiles x 2 row-tiles (R19 shape).
__global__ __launch_bounds__(1024, 2) void k_pref(
    const float* __restrict__ resid,          // [MM][DIMD]
    const unsigned short* __restrict__ cb16,  // stage slice [NE][DIMD]
    const float* __restrict__ bK,             // stage slice [NE]
    float* __restrict__ avS,                  // [MM] scratch
    int*   __restrict__ cntS,                 // [MM] scratch
    int*   __restrict__ candS) {              // [MM][CAP] scratch
  __shared__ float residS[TM][DIMD + 4];
  __shared__ unsigned short sX[TM][DIMD + 8];
  __shared__ float  sBK[NE];
  __shared__ float  av_s[TM];
  __shared__ float  candD[TM][NW];
  __shared__ float  thrS[TM];
  __shared__ int    cnt[TM];
  __shared__ int    candL[TM][CAP];

  const int tid  = threadIdx.x;
  const int lane = tid & 63;
  const int wv   = tid >> 6;       // wave 0..15
  const int rowBase = blockIdx.x * TM;
  const int r32 = tid >> 5;        // row 0..31
  const int j32 = tid & 31;
  const int d0  = j32 * 8;
  const int m16  = lane & 15;
  const int quad = lane >> 4;

  // coalesced resid -> residS: 32 rows x 64 f4 = 2048 float4, 2 per thread
  // (R21 BUG was k<8 here: 8192 f4 -> row index up to 127 -> LDS OOB smash)
  {
    const float4* src = (const float4*)(resid + (size_t)rowBase * DIMD);
    #pragma unroll
    for (int k = 0; k < 2; ++k) {
      const int i = tid + k * 1024;            // f4 index, 2048 total
      const int row = i >> 6, col = (i & 63) << 2;
      *(float4*)&residS[row][col] = src[i];
    }
  }
  sBK[tid] = bK[tid];
  __syncthreads();

  // av (FROZEN x32 tree on identical bits) + cnt reset + bf16 staging
  {
    float av = np_sumsq_256_x32(&residS[r32][0], j32);
    if (j32 == 0) av_s[r32] = av;
  }
  if (tid < TM) cnt[tid] = 0;
  {
    const float* rp = &residS[r32][d0];
    const float4 f0 = *(const float4*)rp;
    const float4 f1 = *(const float4*)(rp + 4);
    unsigned short t[8] = {f2bf(f0.x), f2bf(f0.y), f2bf(f0.z), f2bf(f0.w),
                           f2bf(f1.x), f2bf(f1.y), f2bf(f1.z), f2bf(f1.w)};
    *(v8s*)&sX[r32][d0] = *(v8s*)t;
  }
  __syncthreads();

  // per-wave bmax over sBK (fp32 fmax == old atomicMax value bit-exactly)
  float bmx;
  {
    float bm = sBK[lane];
    #pragma unroll
    for (int t = 1; t < 16; ++t) bm = fmaxf(bm, sBK[lane + t * 64]);
    #pragma unroll
    for (int off = 32; off; off >>= 1) bm = fmaxf(bm, __shfl_xor(bm, off, 64));
    bmx = bm;
  }

  // MFMA: 2 row-tiles x 4 col-tiles per wave; per kc all 4 B-fragments
  // batched; d~ kc-order identical to R19/R20 -> bit-identical.
  v4f acc[2][4];
  #pragma unroll
  for (int mt = 0; mt < 2; ++mt)
    #pragma unroll
    for (int ct = 0; ct < 4; ++ct) acc[mt][ct] = (v4f)(0.f);
  const unsigned short* bptr =
      cb16 + ((size_t)(wv * 64 + m16)) * DIMD + quad * 8;
  #pragma unroll
  for (int kc = 0; kc < 8; ++kc) {
    v8s bfr[4];
    #pragma unroll
    for (int ct = 0; ct < 4; ++ct)
      bfr[ct] = *(const v8s*)(bptr + (size_t)ct * 16 * DIMD + kc * 32);
    v8s a0 = *(const v8s*)&sX[m16][kc * 32 + quad * 8];
    v8s a1 = *(const v8s*)&sX[16 + m16][kc * 32 + quad * 8];
    #pragma unroll
    for (int ct = 0; ct < 4; ++ct) {
      acc[0][ct] = __builtin_amdgcn_mfma_f32_16x16x32_bf16(a0, bfr[ct], acc[0][ct], 0, 0, 0);
      acc[1][ct] = __builtin_amdgcn_mfma_f32_16x16x32_bf16(a1, bfr[ct], acc[1][ct], 0, 0, 0);
    }
  }

  // d~ = a - 2*M~ + b  (D: row = mt*16 + quad*4 + v, col = m16)
  float av8[2][4];
  #pragma unroll
  for (int mt = 0; mt < 2; ++mt)
    #pragma unroll
    for (int v = 0; v < 4; ++v) av8[mt][v] = av_s[mt * 16 + quad * 4 + v];
  #pragma unroll
  for (int ct = 0; ct < 4; ++ct) {
    const float bv = sBK[wv * 64 + ct * 16 + m16];
    #pragma unroll
    for (int mt = 0; mt < 2; ++mt)
      #pragma unroll
      for (int v = 0; v < 4; ++v)
        acc[mt][ct][v] = av8[mt][v] - 2.0f * acc[mt][ct][v] + bv;
  }

  // per-row wave min -> candD
  #pragma unroll
  for (int mt = 0; mt < 2; ++mt) {
    float vmin[4];
    #pragma unroll
    for (int v = 0; v < 4; ++v) {
      vmin[v] = acc[mt][0][v];
      #pragma unroll
      for (int ct = 1; ct < 4; ++ct) vmin[v] = fminf(vmin[v], acc[mt][ct][v]);
      #pragma unroll
      for (int off = 1; off < 16; off <<= 1)
        vmin[v] = fminf(vmin[v], __shfl_xor(vmin[v], off, 64));
    }
    if (m16 == 0) {
      #pragma unroll
      for (int v = 0; v < 4; ++v) candD[mt * 16 + quad * 4 + v][wv] = vmin[v];
    }
  }
  __syncthreads();
  if (tid < TM) {
    float bd = candD[tid][0];
    #pragma unroll
    for (int w = 1; w < NW; ++w) bd = fminf(bd, candD[tid][w]);
    // certified margin: 2*2^-8*sqrt(a*bmax) needed; 2^-5*sqrt(.)+0.1 = 8x slack
    thrS[tid] = bd + 0.03125f * sqrtf(av_s[tid] * bmx) + 0.1f;
  }
  __syncthreads();

  // gather candidates (same predicate/CAP as R19/R20)
  #pragma unroll
  for (int ct = 0; ct < 4; ++ct) {
    const int code = wv * 64 + ct * 16 + m16;
    #pragma unroll
    for (int mt = 0; mt < 2; ++mt) {
      #pragma unroll
      for (int v = 0; v < 4; ++v) {
        const int row = mt * 16 + quad * 4 + v;
        if (acc[mt][ct][v] <= thrS[row]) {
          int pos = atomicAdd(&cnt[row], 1);
          if (pos < CAP) candL[row][pos] = code;
        }
      }
    }
  }
  __syncthreads();

  // write out: av/cnt (32 rows) + candL (32x32, coalesced)
  if (tid < TM) {
    cntS[rowBase + tid] = cnt[tid];
    avS[rowBase + tid] = av_s[tid];
  }
  candS[(size_t)(rowBase + r32) * CAP + j32] = candL[r32][j32];
}

// rerank + STE: wave-autonomous, 2 rows/wave (32 lanes/row), NO barriers.
// 2048 blocks x 256 threads = 8 rows/block.
__global__ __launch_bounds__(256, 4) void k_rank(
    float* __restrict__ resid,                // [MM][DIMD], updated in place
    const float* __restrict__ cb,             // stage slice fp32
    const float* __restrict__ bK,             // stage slice
    const float* __restrict__ avS,            // [MM]
    const int*   __restrict__ cntS,           // [MM]
    const int*   __restrict__ candS,          // [MM][CAP]
    float* __restrict__ idx_out,              // [MM] stage slice
    double* __restrict__ lossP) {             // 64 slots for this stage
  const int tid  = threadIdx.x;
  const int lane = tid & 63;
  const int wv   = tid >> 6;
  const int half = lane >> 5;
  const int l32  = lane & 31;
  const int row  = blockIdx.x * 8 + wv * 2 + half;
  const float* xp = resid + (size_t)row * DIMD;
  const float a = avS[row];
  const int cntv = cntS[row];
  const int n = (cntv <= CAP) ? cntv : 0;     // overflow -> exact full scan

  float bd = 3.4e38f;
  int bi = 0x7fffffff;
  if (l32 < n) {
    const int code = candS[(size_t)row * CAP + l32];
    bd = np_dist_f4(xp, cb + (size_t)code * DIMD, a, bK[code]);  // FROZEN
    bi = code;
  }
  if (cntv > CAP) {  // rare: exact scan, 32 codes/lane; lexicographic min
    #pragma unroll 1
    for (int k = 0; k < 32; ++k) {
      const int code = l32 + k * 32;
      float d = np_dist_f4(xp, cb + (size_t)code * DIMD, a, bK[code]);
      if (d < bd || (d == bd && code < bi)) { bd = d; bi = code; }
    }
  }
  // reduce over the 32-lane row group: exact lexicographic (d, code) min ==
  // old serial scan result (same distance set, tie -> lower code)
  #pragma unroll
  for (int off = 16; off; off >>= 1) {
    float vd = __shfl_xor(bd, off, 64);
    int vi = __shfl_xor(bi, off, 64);
    if (vd < bd || (vd == bd && vi < bi)) { bd = vd; bi = vi; }
  }
  if (l32 == 0) idx_out[row] = (float)bi;

  // STE update — FROZEN chain, lane covers 8 floats (d0 = l32*8, same split)
  const int codeB = bi;
  const int d0 = l32 * 8;
  double lsum = 0.0;
  #pragma unroll
  for (int h = 0; h < 2; ++h) {
    const int d = d0 + h * 4;
    const float4 ev = *(const float4*)(cb + (size_t)codeB * DIMD + d);
    const float4 rv = *(const float4*)(xp + d);
    float t0 = __fsub_rn(ev.x, rv.x), u0 = __fadd_rn(rv.x, t0);
    float t1 = __fsub_rn(ev.y, rv.y), u1 = __fadd_rn(rv.y, t1);
    float t2 = __fsub_rn(ev.z, rv.z), u2 = __fadd_rn(rv.z, t2);
    float t3 = __fsub_rn(ev.w, rv.w), u3 = __fadd_rn(rv.w, t3);
    *(float4*)(resid + (size_t)row * DIMD + d) =
        make_float4(__fsub_rn(rv.x, u0), __fsub_rn(rv.y, u1),
                    __fsub_rn(rv.z, u2), __fsub_rn(rv.w, u3));
    lsum += (double)__fmul_rn(t0, t0) + (double)__fmul_rn(t1, t1) +
            (double)__fmul_rn(t2, t2) + (double)__fmul_rn(t3, t3);
  }
  #pragma unroll
  for (int off = 32; off; off >>= 1) lsum += __shfl_xor(lsum, off, 64);
  if (lane == 0) atomicAdd(lossP + (blockIdx.x & 63), lsum);
}

// out_q = fl(x - resid_final)  (R12's k_final op)
__global__ __launch_bounds__(256) void k_final(const float* __restrict__ x,
                                               const float* __restrict__ resid,
                                               float* __restrict__ out_q) {
  size_t i = (size_t)blockIdx.x * blockDim.x + threadIdx.x;
  const size_t n4 = (size_t)MM * DIMD / 4;
  const float4* xs = (const float4*)x;
  const float4* rd = (const float4*)resid;
  float4* q = (float4*)out_q;
  for (size_t p = i; p < n4; p += (size_t)gridDim.x * blockDim.x) {
    float4 a = xs[p], b = rd[p];
    q[p] = make_float4(__fsub_rn(a.x, b.x), __fsub_rn(a.y, b.y),
                       __fsub_rn(a.z, b.z), __fsub_rn(a.w, b.w));
  }
}

__global__ __launch_bounds__(64) void k_loss(const double* __restrict__ lossP,
                                             float* __restrict__ out_loss) {
  if (threadIdx.x < QQ) {
    double s = 0.0;
    for (int i = 0; i < 64; ++i) s += lossP[(size_t)threadIdx.x * 64 + i];
    out_loss[threadIdx.x] = (float)(s * (1.0 / (double)((size_t)MM * DIMD)));
  }
}

extern "C" void kernel_launch(void* const* d_in, const int* in_sizes, int n_in,
                              void* d_out, int out_size, void* d_ws, size_t ws_size,
                              hipStream_t stream) {
  const float* x = (const float*)d_in[0];        // [8,2048,256]
  const float* cb = (const float*)d_in[1];       // [4,1024,256]
  float* ws = (float*)d_ws;
  unsigned short* cb16 = (unsigned short*)ws;    // 1,048,576 ushort
  float* bK = ws + 524288;
  double* lossP = (double*)(ws + 528384);        // [QQ][64]
  float* resid = ws + 528896;                    // [MM][DIMD]

  float* out = (float*)d_out;
  float* out_idx = out + (size_t)MM * DIMD;      // 4,194,304
  float* out_loss = out_idx + (size_t)QQ * MM;   // +65,536

  // out_q-region scratch (free until k_final)
  int*   candS = (int*)out;                      // [MM][CAP] = 524,288 ints
  int*   cntS  = (int*)(out + 524288);           // [MM]
  float* avS   = out + 540672;                   // [MM]  (ends 557,056 < 4M)

  k_prep<<<dim3(QQ * NE / 8), dim3(256), 0, stream>>>(cb, x, cb16, bK, resid,
                                                      lossP);
  for (int qi = 0; qi < QQ; ++qi) {
    k_pref<<<dim3(MM / TM), dim3(1024), 0, stream>>>(
        resid, cb16 + (size_t)qi * NE * DIMD, bK + (size_t)qi * NE,
        avS, cntS, candS);
    k_rank<<<dim3(MM / 8), dim3(256), 0, stream>>>(
        resid, cb + (size_t)qi * NE * DIMD, bK + (size_t)qi * NE,
        avS, cntS, candS, out_idx + (size_t)qi * MM,
        lossP + (size_t)qi * 64);
  }
  k_final<<<dim3(2048), dim3(256), 0, stream>>>(x, resid, out);
  k_loss<<<dim3(1), dim3(64), 0, stream>>>(lossP, out_loss);
}

// Round 11
// 368.826 us; speedup vs baseline: 1.1157x; 1.1157x over previous
//
#include <hip/hip_runtime.h>

// ResidualVQ: Q=4, N_EMBED=1024, DIM=256, B=8, S=2048 (fp32).
// out = [quantized 8*2048*256][indices-as-float 4*8*2048][losses 4]
//
// R23: R18 monolith (best: 323us) + the two fixes R22's split ablation
// exposed:
//  (1) CAP 32->64 (dynamic LDS 72KB): rows w/ 32<cnt<=64 take the candidate
//      path instead of the serial exact fallback (32 chained np_dist = ~17us
//      straggler per overflow row — the frozen 256-fmaf chain is ~1300cy).
//      Certified-superset property => candidate-set argmin == full-scan
//      argmin incl. ties -> outputs bit-identical.
//  (2) phase fusion: next stage's sX(bf16), av, sBK, cnt-reset move into the
//      STE phase (values already in registers); av via an in-register shfl
//      tree with scalar-identical leaf pairing (IEEE fadd commutativity =>
//      bit-exact). Removes one phase + barrier per stage.
// Certified exact re-rank structure FROZEN (R11-R22): bf16-MFMA prefilter,
// tau margin 8x slack, frozen np fp32 distance chain, tie -> lower index,
// frozen STE recursion. Outputs bit-identical to R18.
#define QQ   4
#define NE   1024
#define DIMD 256
#define MM   16384
#define TM   32
#define NW   8      // waves per block (512 threads)
#define CAP  64     // candidate slots per row (was 32)

typedef short v8s __attribute__((ext_vector_type(8)));   // 8 x bf16
typedef float v4f __attribute__((ext_vector_type(4)));

// ws layout (float offsets):
//  cb16  [QQ][NE][DIMD] ushort @ 0        (524,288 floats)
//  bK    [QQ][NE]              @ 524,288  (4,096)
//  lossP double[QQ][64]        @ 528,384  (byte 2,113,536 %8==0; 512 floats)
//  done  uint                  @ 528,896

struct SLds {
  double lossW[NW];                  // 8B-aligned first
  float  residF[TM][DIMD + 4];       // fp32 residual, all 4 stages
  unsigned short sX[TM][DIMD + 8];   // bf16 rows (base/stride 16B-aligned)
  float  sBK[NE];
  float  av_s[TM];
  float  candD[TM][NW];
  float  thrS[TM];
  int    cnt[TM];
  int    candL[TM][CAP];
  float  dcD[TM][CAP];
  int    bcode[TM];
  float  fwD[NW];
  int    fwI[NW];
};  // ~72,320 B dynamic LDS

__device__ __forceinline__ unsigned short f2bf(float f) {  // RNE fp32->bf16
  unsigned u = __float_as_uint(f);
  return (unsigned short)((u + 0x7FFFu + ((u >> 16) & 1u)) >> 16);
}

// FROZEN numpy pairwise sumsq of 256 f32, over a 32-aligned group of 32 lanes
// (j = lane-in-group). Valid on j==0. Identical op tree/pairing as scalar.
// (k_prep only.)
__device__ __forceinline__ float np_sumsq_256_x32(const float* __restrict__ p,
                                                  int j) {
  const int bi = j >> 4, L = j & 15;
  const float* q = p + bi * 128 + L;
  float s0 = __fmul_rn(q[0], q[0]);
  float s1 = __fmul_rn(q[16], q[16]);
  float s2 = __fmul_rn(q[32], q[32]);
  float s3 = __fmul_rn(q[48], q[48]);
  float s4 = __fmul_rn(q[64], q[64]);
  float s5 = __fmul_rn(q[80], q[80]);
  float s6 = __fmul_rn(q[96], q[96]);
  float s7 = __fmul_rn(q[112], q[112]);
  float w = __fadd_rn(__fadd_rn(__fadd_rn(s0, s1), __fadd_rn(s2, s3)),
                      __fadd_rn(__fadd_rn(s4, s5), __fadd_rn(s6, s7)));
  float u  = __fadd_rn(w,  __shfl_down(w, 8, 64));   // valid L<8
  float t  = __fadd_rn(u,  __shfl_down(u, 4, 64));   // valid L<4
  float r2 = __fadd_rn(t,  __shfl_down(t, 2, 64));   // valid L<2
  float bb = __fadd_rn(r2, __shfl_down(r2, 1, 64));  // valid L==0 -> blk[bi]
  return __fadd_rn(bb, __shfl_down(bb, 16, 64));     // valid j==0
}

// FROZEN av from REGISTERS across the 16-lane row group. Thread (row,j16)
// owns row elements [16*j16, 16*j16+16) = leaves s(c=j16&7, L=0..15) of
// block bi=j16>>3. shfl_xor over c (1,2,4) builds w[L] with the exact
// ((s0+s1)+(s2+s3))+((s4+s5)+(s6+s7)) pairing — per-lane operand swaps are
// IEEE-commutative => bit-identical. u/t/r2/blk complete IN-LANE with the
// scalar pairing; blk0+blk1 via shfl_xor 8. All 16 lanes return the exact
// scalar np_sumsq value.
__device__ __forceinline__ float np_sumsq_256_reg(const float* __restrict__ v) {
  float s[16];
  #pragma unroll
  for (int L = 0; L < 16; ++L) s[L] = __fmul_rn(v[L], v[L]);
  #pragma unroll
  for (int m = 1; m <= 4; m <<= 1) {
    #pragma unroll
    for (int L = 0; L < 16; ++L) {
      float o = __shfl_xor(s[L], m, 64);
      s[L] = __fadd_rn(s[L], o);
    }
  }
  float u[8], t[4], r2[2];
  #pragma unroll
  for (int L = 0; L < 8; ++L) u[L] = __fadd_rn(s[L], s[L + 8]);
  #pragma unroll
  for (int L = 0; L < 4; ++L) t[L] = __fadd_rn(u[L], u[L + 4]);
  #pragma unroll
  for (int L = 0; L < 2; ++L) r2[L] = __fadd_rn(t[L], t[L + 2]);
  float blk = __fadd_rn(r2[0], r2[1]);
  float o = __shfl_xor(blk, 8, 64);
  return __fadd_rn(blk, o);
}

// frozen np distance, float4-load pipelined (IDENTICAL fma sequence/order)
__device__ __forceinline__ float np_dist_f4(const float* __restrict__ xp,
                                            const float* __restrict__ ep,
                                            float a, float b) {
  float m = 0.f;
  #pragma unroll 16
  for (int d4 = 0; d4 < DIMD / 4; ++d4) {
    const float4 xv = *(const float4*)(xp + d4 * 4);
    const float4 ev = *(const float4*)(ep + d4 * 4);
    m = fmaf(xv.x, ev.x, m);
    m = fmaf(xv.y, ev.y, m);
    m = fmaf(xv.z, ev.z, m);
    m = fmaf(xv.w, ev.w, m);
  }
  return __fadd_rn(__fsub_rn(a, __fmul_rn(2.0f, m)), b);
}

// fused prep: bf16 conversion of all codebooks + bK (frozen np sumsq) +
// zero lossP/done. 1024 blocks x 256 threads.
__global__ __launch_bounds__(256) void k_prep(const float* __restrict__ cb,
                                              unsigned short* __restrict__ cb16,
                                              float* __restrict__ bK,
                                              double* __restrict__ lossP,
                                              unsigned* __restrict__ done) {
  const int g = blockIdx.x * 256 + threadIdx.x;  // 0..262143
  {  // cb16: 4 elements per thread, exactly covers QQ*NE*DIMD
    const int i = g * 4;
    float4 f = *(const float4*)(cb + i);
    unsigned short t[4] = {f2bf(f.x), f2bf(f.y), f2bf(f.z), f2bf(f.w)};
    *(short4*)(cb16 + i) = *(short4*)t;
  }
  if (g < QQ * NE * 32) {  // bK: 32 lanes per row (frozen np tree)
    const int row = g >> 5, j = g & 31;
    float b = np_sumsq_256_x32(cb + (size_t)row * DIMD, j);
    if (j == 0) bK[row] = b;
  }
  if (g < QQ * 64) lossP[g] = 0.0;
  if (g == 0) *done = 0u;
}

// 512 threads = 8 waves; block owns TM=32 rows through ALL 4 stages.
// Wave w covers codes [w*128,(w+1)*128): 8 col-tiles x 2 row-tiles.
// launch_bounds(512,2): 256 regs/wave -> acc[2][8]+bfr[8] fit, zero spill.
__global__ __launch_bounds__(512, 2) void k_fused(
    const float* __restrict__ x,              // [MM][DIMD]
    const unsigned short* __restrict__ cb16a, // [QQ][NE][DIMD] bf16
    const float* __restrict__ cba,            // [QQ][NE][DIMD] fp32
    const float* __restrict__ bKa,            // [QQ][NE]
    double* __restrict__ lossP,               // [QQ][64]
    unsigned* __restrict__ doneCnt,           // grid done counter
    float* __restrict__ out_q,                // [MM][DIMD]
    float* __restrict__ idx_out,              // [QQ][MM] floats
    float* __restrict__ out_loss) {           // [QQ]
  extern __shared__ char smem_raw[];
  SLds& S = *reinterpret_cast<SLds*>(smem_raw);

  const int tid  = threadIdx.x;
  const int lane = tid & 63;
  const int wv   = tid >> 6;
  const int rowBase = blockIdx.x * TM;
  const int r16 = tid >> 4;        // row 0..31 (16 threads per row)
  const int j16 = tid & 15;        // lane in row-group
  const int d0  = j16 * 16;        // 16 floats per thread per row
  const int m16  = lane & 15;
  const int quad = lane >> 4;

  // init: x -> residF + sX(bf16) + av (in-register frozen tree) + cnt reset
  // + sBK for stage 0. ONE barrier covers all of it.
  {
    const float* xp = x + (size_t)(rowBase + r16) * DIMD + d0;
    float rn[16];
    #pragma unroll
    for (int h = 0; h < 4; ++h) {
      const float4 a = *(const float4*)(xp + h * 4);
      rn[h * 4 + 0] = a.x; rn[h * 4 + 1] = a.y;
      rn[h * 4 + 2] = a.z; rn[h * 4 + 3] = a.w;
      *(float4*)&S.residF[r16][d0 + h * 4] = a;
    }
    #pragma unroll
    for (int h = 0; h < 2; ++h) {
      unsigned short t8[8];
      #pragma unroll
      for (int k = 0; k < 8; ++k) t8[k] = f2bf(rn[h * 8 + k]);
      *(v8s*)&S.sX[r16][d0 + h * 8] = *(v8s*)t8;
    }
    float av = np_sumsq_256_reg(rn);
    if (j16 == 0) S.av_s[r16] = av;
  }
  if (tid < TM) S.cnt[tid] = 0;
  S.sBK[tid] = bKa[tid];
  S.sBK[tid + 512] = bKa[tid + 512];
  __syncthreads();

  #pragma unroll 1
  for (int qi = 0; qi < QQ; ++qi) {
    const unsigned short* cb16 = cb16a + (size_t)qi * NE * DIMD;
    const float* cb = cba + (size_t)qi * NE * DIMD;

    // per-wave bmax over sBK (fp32 fmax == old atomicMax value bit-exactly)
    float bmx;
    {
      float bm = S.sBK[lane];
      #pragma unroll
      for (int t = 1; t < 16; ++t) bm = fmaxf(bm, S.sBK[lane + t * 64]);
      #pragma unroll
      for (int off = 32; off; off >>= 1) bm = fmaxf(bm, __shfl_xor(bm, off, 64));
      bmx = bm;
    }

    // MFMA: M~[row][code], 2 row-tiles x 8 col-tiles per wave; per kc all 8
    // B-fragments batched (8 dwordx4 in flight), 16 MFMAs.
    v4f acc[2][8];
    #pragma unroll
    for (int mt = 0; mt < 2; ++mt)
      #pragma unroll
      for (int ct = 0; ct < 8; ++ct) acc[mt][ct] = (v4f)(0.f);
    const unsigned short* bptr =
        cb16 + ((size_t)(wv * 128 + m16)) * DIMD + quad * 8;
    #pragma unroll
    for (int kc = 0; kc < 8; ++kc) {
      v8s bfr[8];
      #pragma unroll
      for (int ct = 0; ct < 8; ++ct)
        bfr[ct] = *(const v8s*)(bptr + (size_t)ct * 16 * DIMD + kc * 32);
      v8s a0 = *(const v8s*)&S.sX[m16][kc * 32 + quad * 8];
      v8s a1 = *(const v8s*)&S.sX[16 + m16][kc * 32 + quad * 8];
      #pragma unroll
      for (int ct = 0; ct < 8; ++ct) {
        acc[0][ct] = __builtin_amdgcn_mfma_f32_16x16x32_bf16(a0, bfr[ct], acc[0][ct], 0, 0, 0);
        acc[1][ct] = __builtin_amdgcn_mfma_f32_16x16x32_bf16(a1, bfr[ct], acc[1][ct], 0, 0, 0);
      }
    }

    // approx dist in-place: d~ = a - 2*M~ + b  (D: row=mt*16+quad*4+v, col=m16)
    float av8[2][4];
    #pragma unroll
    for (int mt = 0; mt < 2; ++mt)
      #pragma unroll
      for (int v = 0; v < 4; ++v) av8[mt][v] = S.av_s[mt * 16 + quad * 4 + v];
    #pragma unroll
    for (int ct = 0; ct < 8; ++ct) {
      const float bv = S.sBK[wv * 128 + ct * 16 + m16];
      #pragma unroll
      for (int mt = 0; mt < 2; ++mt)
        #pragma unroll
        for (int v = 0; v < 4; ++v)
          acc[mt][ct][v] = av8[mt][v] - 2.0f * acc[mt][ct][v] + bv;
    }

    // per-row min: over ct, then across the 16 lanes of each quad
    #pragma unroll
    for (int mt = 0; mt < 2; ++mt) {
      float vmin[4];
      #pragma unroll
      for (int v = 0; v < 4; ++v) {
        vmin[v] = acc[mt][0][v];
        #pragma unroll
        for (int ct = 1; ct < 8; ++ct) vmin[v] = fminf(vmin[v], acc[mt][ct][v]);
        #pragma unroll
        for (int off = 1; off < 16; off <<= 1)
          vmin[v] = fminf(vmin[v], __shfl_xor(vmin[v], off, 64));
      }
      if (m16 == 0) {
        #pragma unroll
        for (int v = 0; v < 4; ++v) S.candD[mt * 16 + quad * 4 + v][wv] = vmin[v];
      }
    }
    __syncthreads();
    if (tid < TM) {
      float bd = S.candD[tid][0];
      #pragma unroll
      for (int w = 1; w < NW; ++w) bd = fminf(bd, S.candD[tid][w]);
      // certified margin: 2*2^-8*sqrt(a*bmax) needed; 2^-5*sqrt(.)+0.1 = 8x slack
      S.thrS[tid] = bd + 0.03125f * sqrtf(S.av_s[tid] * bmx) + 0.1f;
    }
    __syncthreads();

    // gather candidates (CAP=64; same predicate; acc live across barriers —
    // the 256-reg budget holds it without spill, R18-proven)
    #pragma unroll
    for (int ct = 0; ct < 8; ++ct) {
      const int code = wv * 128 + ct * 16 + m16;
      #pragma unroll
      for (int mt = 0; mt < 2; ++mt) {
        #pragma unroll
        for (int v = 0; v < 4; ++v) {
          const int row = mt * 16 + quad * 4 + v;
          if (acc[mt][ct][v] <= S.thrS[row]) {
            int pos = atomicAdd(&S.cnt[row], 1);
            if (pos < CAP) S.candL[row][pos] = code;
          }
        }
      }
    }
    __syncthreads();

    // exact (frozen) distance per candidate: thread (row,j16) covers slots
    // j16+16k, k=0..3 (x from LDS: identical fp32 values, identical fma order)
    {
      const int n = (S.cnt[r16] <= CAP) ? S.cnt[r16] : 0;  // overflow -> fallback
      #pragma unroll
      for (int k = 0; k < 4; ++k) {
        const int ci = j16 + k * 16;
        if (ci < n) {
          const int code = S.candL[r16][ci];
          S.dcD[r16][ci] = np_dist_f4(&S.residF[r16][0],
                                      cb + (size_t)code * DIMD,
                                      S.av_s[r16], S.sBK[code]);
        }
      }
    }
    __syncthreads();

    // cooperative fallback for overflow rows (now cnt>64 only, ~never):
    for (int r = 0; r < TM; ++r) {
      if (S.cnt[r] > CAP) {
        const float* xp = &S.residF[r][0];
        const float a = S.av_s[r];
        float d1 = np_dist_f4(xp, cb + (size_t)tid * DIMD, a, S.sBK[tid]);
        float d2 = np_dist_f4(xp, cb + (size_t)(tid + 512) * DIMD, a, S.sBK[tid + 512]);
        int i1 = tid;
        if (d2 < d1) { d1 = d2; i1 = tid + 512; }  // strict <: lower idx on tie
        #pragma unroll
        for (int off = 32; off; off >>= 1) {
          float vd = __shfl_xor(d1, off, 64);
          int vi = __shfl_xor(i1, off, 64);
          if (vd < d1 || (vd == d1 && vi < i1)) { d1 = vd; i1 = vi; }
        }
        if (lane == 0) { S.fwD[wv] = d1; S.fwI[wv] = i1; }
        __syncthreads();
        if (tid == 0) {
          float bd = S.fwD[0];
          int bi = S.fwI[0];
          #pragma unroll
          for (int w = 1; w < NW; ++w) {
            if (S.fwD[w] < bd || (S.fwD[w] == bd && S.fwI[w] < bi)) {
              bd = S.fwD[w]; bi = S.fwI[w];
            }
          }
          S.bcode[r] = bi;
        }
        __syncthreads();
      }
    }

    if (tid < TM) {
      if (S.cnt[tid] <= CAP) {
        float bd = 3.4e38f;
        int bi = 0x7fffffff;
        for (int ci = 0; ci < S.cnt[tid]; ++ci) {
          float d = S.dcD[tid][ci];
          int code = S.candL[tid][ci];
          if (d < bd || (d == bd && code < bi)) { bd = d; bi = code; }
        }
        S.bcode[tid] = bi;
      }
      idx_out[(size_t)qi * MM + rowBase + tid] = (float)S.bcode[tid];
    }
    __syncthreads();

    // STE (FROZEN chain) + FUSED next-stage staging: sX(bf16 of new resid),
    // av (in-register frozen tree), sBK preload, cnt reset — all here, one
    // barrier. av_s/cnt/sBK overwrites are safe: all their current-stage
    // readers completed before the select barrier above.
    {
      const int codeB = S.bcode[r16];
      double lsum = 0.0;
      float rn[16];
      #pragma unroll
      for (int h = 0; h < 4; ++h) {
        const int d = d0 + h * 4;
        const float4 ev = *(const float4*)(cb + (size_t)codeB * DIMD + d);
        const float4 rv = *(const float4*)&S.residF[r16][d];
        float t0 = __fsub_rn(ev.x, rv.x), u0 = __fadd_rn(rv.x, t0);
        float t1 = __fsub_rn(ev.y, rv.y), u1 = __fadd_rn(rv.y, t1);
        float t2 = __fsub_rn(ev.z, rv.z), u2 = __fadd_rn(rv.z, t2);
        float t3 = __fsub_rn(ev.w, rv.w), u3 = __fadd_rn(rv.w, t3);
        const float4 nv = make_float4(__fsub_rn(rv.x, u0), __fsub_rn(rv.y, u1),
                                      __fsub_rn(rv.z, u2), __fsub_rn(rv.w, u3));
        *(float4*)&S.residF[r16][d] = nv;
        rn[h * 4 + 0] = nv.x; rn[h * 4 + 1] = nv.y;
        rn[h * 4 + 2] = nv.z; rn[h * 4 + 3] = nv.w;
        lsum += (double)__fmul_rn(t0, t0) + (double)__fmul_rn(t1, t1) +
                (double)__fmul_rn(t2, t2) + (double)__fmul_rn(t3, t3);
      }
      if (qi < QQ - 1) {
        #pragma unroll
        for (int h = 0; h < 2; ++h) {
          unsigned short t8[8];
          #pragma unroll
          for (int k = 0; k < 8; ++k) t8[k] = f2bf(rn[h * 8 + k]);
          *(v8s*)&S.sX[r16][d0 + h * 8] = *(v8s*)t8;
        }
        float av = np_sumsq_256_reg(rn);
        if (j16 == 0) S.av_s[r16] = av;
        S.sBK[tid] = bKa[(size_t)(qi + 1) * NE + tid];
        S.sBK[tid + 512] = bKa[(size_t)(qi + 1) * NE + tid + 512];
      }
      if (tid < TM) S.cnt[tid] = 0;
      #pragma unroll
      for (int off = 32; off; off >>= 1) lsum += __shfl_xor(lsum, off, 64);
      if (lane == 0) S.lossW[wv] = lsum;
    }
    __syncthreads();   // orders residF/sX/av/sBK writes before next stage
    if (tid == 0) {
      double s = 0.0;
      #pragma unroll
      for (int w = 0; w < NW; ++w) s += S.lossW[w];
      atomicAdd(lossP + (size_t)qi * 64 + (blockIdx.x & 63), s);
    }
  }

  // epilogue: out_q = fl(x - resid_final)
  {
    const float* xp = x + (size_t)(rowBase + r16) * DIMD + d0;
    float* op = out_q + (size_t)(rowBase + r16) * DIMD + d0;
    #pragma unroll
    for (int h = 0; h < 4; ++h) {
      const float4 a = *(const float4*)(xp + h * 4);
      const float4 b = *(const float4*)&S.residF[r16][d0 + h * 4];
      *(float4*)(op + h * 4) =
          make_float4(__fsub_rn(a.x, b.x), __fsub_rn(a.y, b.y),
                      __fsub_rn(a.z, b.z), __fsub_rn(a.w, b.w));
    }
  }

  // folded k_loss: last block to finish sums lossP (device-scope atomics
  // both sides; __threadfence orders this block's lossP adds first).
  __syncthreads();
  if (tid == 0) {
    __threadfence();
    unsigned old = atomicAdd(doneCnt, 1u);
    S.cnt[0] = (old == (unsigned)(gridDim.x - 1)) ? 1 : 0;
  }
  __syncthreads();
  if (S.cnt[0] && tid < 64) {
    const int qi2 = tid >> 4;
    double s = 0.0;
    #pragma unroll
    for (int i = 0; i < 4; ++i)
      s += atomicAdd(lossP + (size_t)qi2 * 64 + (tid & 15) * 4 + i, 0.0);
    #pragma unroll
    for (int off = 8; off; off >>= 1) s += __shfl_down(s, off, 16);
    if ((tid & 15) == 0)
      out_loss[qi2] = (float)(s * (1.0 / (double)((size_t)MM * DIMD)));
  }
}

extern "C" void kernel_launch(void* const* d_in, const int* in_sizes, int n_in,
                              void* d_out, int out_size, void* d_ws, size_t ws_size,
                              hipStream_t stream) {
  const float* x = (const float*)d_in[0];        // [8,2048,256]
  const float* cb = (const float*)d_in[1];       // [4,1024,256]
  float* ws = (float*)d_ws;
  unsigned short* cb16 = (unsigned short*)ws;    // 1,048,576 ushort
  float* bK = ws + 524288;
  double* lossP = (double*)(ws + 528384);        // [QQ][64], byte off %8==0
  unsigned* done = (unsigned*)(ws + 528896);

  float* out = (float*)d_out;
  float* out_idx = out + (size_t)MM * DIMD;      // 4,194,304
  float* out_loss = out_idx + (size_t)QQ * MM;   // +65,536

  static bool attr_set = false;
  if (!attr_set) {
    hipFuncSetAttribute(reinterpret_cast<const void*>(k_fused),
                        hipFuncAttributeMaxDynamicSharedMemorySize,
                        (int)sizeof(SLds));
    attr_set = true;
  }

  k_prep<<<dim3(1024), dim3(256), 0, stream>>>(cb, cb16, bK, lossP, done);
  k_fused<<<dim3(MM / TM), dim3(512), sizeof(SLds), stream>>>(
      x, cb16, cb, bK, lossP, done, out, out_idx, out_loss);
}

// Round 12
// 292.807 us; speedup vs baseline: 1.4054x; 1.2596x over previous
//
#include <hip/hip_runtime.h>

// ResidualVQ: Q=4, N_EMBED=1024, DIM=256, B=8, S=2048 (fp32).
// out = [quantized 8*2048*256][indices-as-float 4*8*2048][losses 4]
//
// R24: exact R18 (best: 323us total / 279 k_fused, clean spill profile) +
// ONE change: cb16 stored TRANSPOSED as cbT[qi][kc][code][quad][8] so each
// MFMA B-fragment load instruction's 64 lanes cover one CONTIGUOUS 1KB block
// (16 cache lines/instr vs 64 with the row-major layout -> 4x less address-
// unit serialization; 8KB contiguous per (wave,kc) for L2). Theory: the
// session's recurring "all pipes <10% busy yet slow" signature is TA/TCP
// front-end serialization of maximally-uncoalesced vector loads — a cost
// visible in no SQ counter. R23's CAP=64 + phase fusion are REVERTED (they
// re-triggered spill, WRITE 22->80MB, and doubled bank conflicts).
// k_prep rebuilt R22-style (LDS-staged 8 rows/block, verified) to emit cbT
// + bK. cbT is consumed only by the MFMA B loads -> d~ bit-identical.
// Certified exact re-rank structure FROZEN (R11-R23): bf16-MFMA prefilter,
// tau margin 8x slack, frozen np fp32 distance chain, tie -> lower index,
// frozen STE recursion. Outputs bit-identical to R18.
#define QQ   4
#define NE   1024
#define DIMD 256
#define MM   16384
#define TM   32
#define NW   8      // waves per block (512 threads)
#define CAP  32     // candidate slots per row

typedef short v8s __attribute__((ext_vector_type(8)));   // 8 x bf16
typedef float v4f __attribute__((ext_vector_type(4)));

// ws layout (float offsets):
//  cbT   [QQ][8][NE][4][8] ushort @ 0     (524,288 floats)  [kc][code][quad]
//  bK    [QQ][NE]              @ 524,288  (4,096)
//  lossP double[QQ][64]        @ 528,384  (byte 2,113,536 %8==0; 512 floats)
//  done  uint                  @ 528,896

__device__ __forceinline__ unsigned short f2bf(float f) {  // RNE fp32->bf16
  unsigned u = __float_as_uint(f);
  return (unsigned short)((u + 0x7FFFu + ((u >> 16) & 1u)) >> 16);
}

// FROZEN numpy pairwise sumsq of 256 f32, over a 32-aligned group of 32 lanes
// (j = lane-in-group). Valid on j==0. Identical op tree/pairing as scalar.
__device__ __forceinline__ float np_sumsq_256_x32(const float* __restrict__ p,
                                                  int j) {
  const int bi = j >> 4, L = j & 15;
  const float* q = p + bi * 128 + L;
  float s0 = __fmul_rn(q[0], q[0]);
  float s1 = __fmul_rn(q[16], q[16]);
  float s2 = __fmul_rn(q[32], q[32]);
  float s3 = __fmul_rn(q[48], q[48]);
  float s4 = __fmul_rn(q[64], q[64]);
  float s5 = __fmul_rn(q[80], q[80]);
  float s6 = __fmul_rn(q[96], q[96]);
  float s7 = __fmul_rn(q[112], q[112]);
  float w = __fadd_rn(__fadd_rn(__fadd_rn(s0, s1), __fadd_rn(s2, s3)),
                      __fadd_rn(__fadd_rn(s4, s5), __fadd_rn(s6, s7)));
  float u  = __fadd_rn(w,  __shfl_down(w, 8, 64));   // valid L<8
  float t  = __fadd_rn(u,  __shfl_down(u, 4, 64));   // valid L<4
  float r2 = __fadd_rn(t,  __shfl_down(t, 2, 64));   // valid L<2
  float bb = __fadd_rn(r2, __shfl_down(r2, 1, 64));  // valid L==0 -> blk[bi]
  return __fadd_rn(bb, __shfl_down(bb, 16, 64));     // valid j==0
}

// Same frozen tree over 16 lanes (j=0..15 in a 16-aligned group); bi serial.
// Operand pairing of every __fadd_rn identical to the scalar chain -> bit-exact.
__device__ __forceinline__ float np_sumsq_256_x16(const float* __restrict__ p,
                                                  int j) {
  float blk[2];
  #pragma unroll
  for (int bi = 0; bi < 2; ++bi) {
    const float* q = p + bi * 128 + j;
    float s0 = __fmul_rn(q[0], q[0]);
    float s1 = __fmul_rn(q[16], q[16]);
    float s2 = __fmul_rn(q[32], q[32]);
    float s3 = __fmul_rn(q[48], q[48]);
    float s4 = __fmul_rn(q[64], q[64]);
    float s5 = __fmul_rn(q[80], q[80]);
    float s6 = __fmul_rn(q[96], q[96]);
    float s7 = __fmul_rn(q[112], q[112]);
    float w = __fadd_rn(__fadd_rn(__fadd_rn(s0, s1), __fadd_rn(s2, s3)),
                        __fadd_rn(__fadd_rn(s4, s5), __fadd_rn(s6, s7)));
    float u  = __fadd_rn(w,  __shfl_down(w, 8, 64));   // valid j<8
    float t  = __fadd_rn(u,  __shfl_down(u, 4, 64));   // valid j<4
    float r2 = __fadd_rn(t,  __shfl_down(t, 2, 64));   // valid j<2
    blk[bi]  = __fadd_rn(r2, __shfl_down(r2, 1, 64));  // valid j==0
  }
  return __fadd_rn(blk[0], blk[1]);                    // valid j==0
}

// frozen np distance, float4-load pipelined (IDENTICAL fma sequence/order)
__device__ __forceinline__ float np_dist_f4(const float* __restrict__ xp,
                                            const float* __restrict__ ep,
                                            float a, float b) {
  float m = 0.f;
  #pragma unroll 16
  for (int d4 = 0; d4 < DIMD / 4; ++d4) {
    const float4 xv = *(const float4*)(xp + d4 * 4);
    const float4 ev = *(const float4*)(ep + d4 * 4);
    m = fmaf(xv.x, ev.x, m);
    m = fmaf(xv.y, ev.y, m);
    m = fmaf(xv.z, ev.z, m);
    m = fmaf(xv.w, ev.w, m);
  }
  return __fadd_rn(__fsub_rn(a, __fmul_rn(2.0f, m)), b);
}

// prep: LDS-stage 8 codebook rows/block (R22-verified pattern) -> bK (frozen
// x32 tree on identical bits) + TRANSPOSED bf16 write cbT[kc][code][quad][8].
// 512 blocks x 256 threads; 8 | 1024 so a block never straddles qi.
__global__ __launch_bounds__(256) void k_prep(const float* __restrict__ cb,
                                              unsigned short* __restrict__ cbT,
                                              float* __restrict__ bK,
                                              double* __restrict__ lossP,
                                              unsigned* __restrict__ done) {
  __shared__ float rowS[8][256];
  const int t = threadIdx.x;
  const int Rbase = blockIdx.x * 8;                  // flat row (qi*NE+code)
  const size_t base = (size_t)Rbase * DIMD;
  {  // coalesced global->LDS: 512 float4, 2 per thread
    const float4* src = (const float4*)(cb + base);
    float4* dst = (float4*)rowS;
    dst[t] = src[t];
    dst[t + 256] = src[t + 256];
  }
  __syncthreads();
  {  // bK: (row r=t>>5, lane j=t&31), frozen x32 tree
    const int r = t >> 5, j = t & 31;
    float b = np_sumsq_256_x32(&rowS[r][0], j);
    if (j == 0) bK[Rbase + r] = b;
  }
  {  // cbT: thread t -> kc=t>>5, s=t&31: code_r=s>>2, quad=s&3 (8 bf16 = 16B)
    const int kc = t >> 5, s = t & 31;
    const int code_r = s >> 2, quad = s & 3;
    const int qi = (Rbase + code_r) >> 10;
    const int code = (Rbase + code_r) & 1023;
    const float* p = &rowS[code_r][kc * 32 + quad * 8];
    unsigned short o[8];
    #pragma unroll
    for (int k = 0; k < 8; ++k) o[k] = f2bf(p[k]);
    unsigned short* dst = cbT + (size_t)qi * NE * DIMD +
                          ((size_t)kc * NE + code) * 32 + quad * 8;
    *(v8s*)dst = *(v8s*)o;
  }
  if (blockIdx.x == 0) lossP[t] = 0.0;               // QQ*64 == 256 slots
  if (blockIdx.x == 0 && t == 0) *done = 0u;
}

// 512 threads = 8 waves; block owns TM=32 rows through ALL 4 stages.
// Wave w covers codes [w*128,(w+1)*128): 8 col-tiles x 2 row-tiles.
// launch_bounds(512,2): 256 regs/wave -> acc[2][8]+bfr[8] fit, zero spill.
__global__ __launch_bounds__(512, 2) void k_fused(
    const float* __restrict__ x,              // [MM][DIMD]
    const unsigned short* __restrict__ cbTa,  // [QQ][8][NE][4][8] bf16
    const float* __restrict__ cba,            // [QQ][NE][DIMD] fp32
    const float* __restrict__ bKa,            // [QQ][NE]
    double* __restrict__ lossP,               // [QQ][64]
    unsigned* __restrict__ doneCnt,           // grid done counter
    float* __restrict__ out_q,                // [MM][DIMD]
    float* __restrict__ idx_out,              // [QQ][MM] floats
    float* __restrict__ out_loss) {           // [QQ]
  __shared__ float residF[TM][DIMD + 4];       // fp32 residual, all 4 stages
  __shared__ unsigned short sX[TM][DIMD + 8];  // bf16 rows
  __shared__ float  sBK[NE];                   // bK staged per stage
  __shared__ float  av_s[TM];
  __shared__ float  candD[TM][NW];
  __shared__ float  thrS[TM];
  __shared__ int    cnt[TM];
  __shared__ int    candL[TM][CAP];
  __shared__ float  dcD[TM][CAP];
  __shared__ int    bcode[TM];
  __shared__ float  fwD[NW];
  __shared__ int    fwI[NW];
  __shared__ double lossW[NW];

  const int tid  = threadIdx.x;
  const int lane = tid & 63;
  const int wv   = tid >> 6;
  const int rowBase = blockIdx.x * TM;
  const int r16 = tid >> 4;        // row 0..31 (16 threads per row)
  const int j16 = tid & 15;        // lane in row-group
  const int d0  = j16 * 16;        // 16 floats per thread per row
  const int m16  = lane & 15;
  const int quad = lane >> 4;

  // x -> residF (exact fp32; stage-0 residual == x)
  {
    const float* xp = x + (size_t)(rowBase + r16) * DIMD + d0;
    #pragma unroll
    for (int h = 0; h < 4; ++h)
      *(float4*)&residF[r16][d0 + h * 4] = *(const float4*)(xp + h * 4);
  }
  __syncthreads();

  #pragma unroll 1
  for (int qi = 0; qi < QQ; ++qi) {
    const unsigned short* cbT = cbTa + (size_t)qi * NE * DIMD;
    const float* cb = cba + (size_t)qi * NE * DIMD;
    const float* bK = bKa + (size_t)qi * NE;

    // av (FROZEN, 16-lane tree, from LDS) + cnt reset + bK->LDS + bf16 staging
    {
      float av = np_sumsq_256_x16(&residF[r16][0], j16);
      if (j16 == 0) av_s[r16] = av;
    }
    if (tid < TM) cnt[tid] = 0;
    sBK[tid] = bK[tid];
    sBK[tid + 512] = bK[tid + 512];
    {
      #pragma unroll
      for (int h = 0; h < 2; ++h) {
        const float* rp = &residF[r16][d0 + h * 8];
        const float4 f0 = *(const float4*)rp;
        const float4 f1 = *(const float4*)(rp + 4);
        unsigned short t[8] = {f2bf(f0.x), f2bf(f0.y), f2bf(f0.z), f2bf(f0.w),
                               f2bf(f1.x), f2bf(f1.y), f2bf(f1.z), f2bf(f1.w)};
        *(v8s*)&sX[r16][d0 + h * 8] = *(v8s*)t;
      }
    }
    __syncthreads();

    // per-wave bmax over sBK (fp32 fmax == old atomicMax value bit-exactly)
    float bmx;
    {
      float bm = sBK[lane];
      #pragma unroll
      for (int t = 1; t < 16; ++t) bm = fmaxf(bm, sBK[lane + t * 64]);
      #pragma unroll
      for (int off = 32; off; off >>= 1) bm = fmaxf(bm, __shfl_xor(bm, off, 64));
      bmx = bm;
    }

    // MFMA: M~[row][code], 2 row-tiles x 8 col-tiles per wave; per kc all 8
    // B-fragments batched. cbT layout: one fragment-load instruction's 64
    // lanes (m16*64B + quad*16B) cover a CONTIGUOUS 1KB block (16 lines).
    // Fragment VALUES identical to R18's row-major loads -> d~ bit-identical.
    v4f acc[2][8];
    #pragma unroll
    for (int mt = 0; mt < 2; ++mt)
      #pragma unroll
      for (int ct = 0; ct < 8; ++ct) acc[mt][ct] = (v4f)(0.f);
    const unsigned short* bptrT =
        cbT + (size_t)(wv * 128 + m16) * 32 + quad * 8;
    #pragma unroll
    for (int kc = 0; kc < 8; ++kc) {
      v8s bfr[8];
      #pragma unroll
      for (int ct = 0; ct < 8; ++ct)
        bfr[ct] = *(const v8s*)(bptrT + (size_t)kc * (NE * 32) + ct * 512);
      v8s a0 = *(const v8s*)&sX[m16][kc * 32 + quad * 8];
      v8s a1 = *(const v8s*)&sX[16 + m16][kc * 32 + quad * 8];
      #pragma unroll
      for (int ct = 0; ct < 8; ++ct) {
        acc[0][ct] = __builtin_amdgcn_mfma_f32_16x16x32_bf16(a0, bfr[ct], acc[0][ct], 0, 0, 0);
        acc[1][ct] = __builtin_amdgcn_mfma_f32_16x16x32_bf16(a1, bfr[ct], acc[1][ct], 0, 0, 0);
      }
    }

    // approx dist in-place: d~ = a - 2*M~ + b  (D: row=mt*16+quad*4+v, col=m16)
    float av8[2][4];
    #pragma unroll
    for (int mt = 0; mt < 2; ++mt)
      #pragma unroll
      for (int v = 0; v < 4; ++v) av8[mt][v] = av_s[mt * 16 + quad * 4 + v];
    #pragma unroll
    for (int ct = 0; ct < 8; ++ct) {
      const float bv = sBK[wv * 128 + ct * 16 + m16];
      #pragma unroll
      for (int mt = 0; mt < 2; ++mt)
        #pragma unroll
        for (int v = 0; v < 4; ++v)
          acc[mt][ct][v] = av8[mt][v] - 2.0f * acc[mt][ct][v] + bv;
    }

    // per-row min: over ct, then across the 16 lanes of each quad
    #pragma unroll
    for (int mt = 0; mt < 2; ++mt) {
      float vmin[4];
      #pragma unroll
      for (int v = 0; v < 4; ++v) {
        vmin[v] = acc[mt][0][v];
        #pragma unroll
        for (int ct = 1; ct < 8; ++ct) vmin[v] = fminf(vmin[v], acc[mt][ct][v]);
        #pragma unroll
        for (int off = 1; off < 16; off <<= 1)
          vmin[v] = fminf(vmin[v], __shfl_xor(vmin[v], off, 64));
      }
      if (m16 == 0) {
        #pragma unroll
        for (int v = 0; v < 4; ++v) candD[mt * 16 + quad * 4 + v][wv] = vmin[v];
      }
    }
    __syncthreads();
    if (tid < TM) {
      float bd = candD[tid][0];
      #pragma unroll
      for (int w = 1; w < NW; ++w) bd = fminf(bd, candD[tid][w]);
      // certified margin: 2*2^-8*sqrt(a*bmax) needed; 2^-5*sqrt(.)+0.1 = 8x slack
      thrS[tid] = bd + 0.03125f * sqrtf(av_s[tid] * bmx) + 0.1f;
    }
    __syncthreads();

    // gather candidates (acc stays live across the barrier; 256-reg budget
    // holds it without spill — R18-proven)
    #pragma unroll
    for (int ct = 0; ct < 8; ++ct) {
      const int code = wv * 128 + ct * 16 + m16;
      #pragma unroll
      for (int mt = 0; mt < 2; ++mt) {
        #pragma unroll
        for (int v = 0; v < 4; ++v) {
          const int row = mt * 16 + quad * 4 + v;
          if (acc[mt][ct][v] <= thrS[row]) {
            int pos = atomicAdd(&cnt[row], 1);
            if (pos < CAP) candL[row][pos] = code;
          }
        }
      }
    }
    __syncthreads();

    // exact (frozen) distance per candidate: thread (row, j16) covers slots
    // j16 and j16+16 (x from LDS: identical fp32 values, identical fma order)
    {
      const int n = (cnt[r16] <= CAP) ? cnt[r16] : 0;  // overflow -> fallback
      if (j16 < n) {
        const int code = candL[r16][j16];
        dcD[r16][j16] = np_dist_f4(&residF[r16][0], cb + (size_t)code * DIMD,
                                   av_s[r16], sBK[code]);
      }
      if (j16 + 16 < n) {
        const int code = candL[r16][j16 + 16];
        dcD[r16][j16 + 16] = np_dist_f4(&residF[r16][0], cb + (size_t)code * DIMD,
                                        av_s[r16], sBK[code]);
      }
    }
    __syncthreads();

    // cooperative fallback for overflow rows (rare): 2 codes/thread, exact
    for (int r = 0; r < TM; ++r) {
      if (cnt[r] > CAP) {
        const float* xp = &residF[r][0];
        const float a = av_s[r];
        float d1 = np_dist_f4(xp, cb + (size_t)tid * DIMD, a, sBK[tid]);
        float d2 = np_dist_f4(xp, cb + (size_t)(tid + 512) * DIMD, a, sBK[tid + 512]);
        int i1 = tid;
        if (d2 < d1) { d1 = d2; i1 = tid + 512; }  // strict <: lower idx on tie
        #pragma unroll
        for (int off = 32; off; off >>= 1) {
          float vd = __shfl_xor(d1, off, 64);
          int vi = __shfl_xor(i1, off, 64);
          if (vd < d1 || (vd == d1 && vi < i1)) { d1 = vd; i1 = vi; }
        }
        if (lane == 0) { fwD[wv] = d1; fwI[wv] = i1; }
        __syncthreads();
        if (tid == 0) {
          float bd = fwD[0];
          int bi = fwI[0];
          #pragma unroll
          for (int w = 1; w < NW; ++w) {
            if (fwD[w] < bd || (fwD[w] == bd && fwI[w] < bi)) {
              bd = fwD[w]; bi = fwI[w];
            }
          }
          bcode[r] = bi;
        }
        __syncthreads();
      }
    }

    if (tid < TM) {
      if (cnt[tid] <= CAP) {
        float bd = 3.4e38f;
        int bi = 0x7fffffff;
        for (int ci = 0; ci < cnt[tid]; ++ci) {
          float d = dcD[tid][ci];
          int code = candL[tid][ci];
          if (d < bd || (d == bd && code < bi)) { bd = d; bi = code; }
        }
        bcode[tid] = bi;
      }
      idx_out[(size_t)qi * MM + rowBase + tid] = (float)bcode[tid];
    }
    __syncthreads();

    // STE update — FROZEN: t=fl(q-r); u=fl(r+t); r'=fl(r-u)  (in-LDS)
    const int codeB = bcode[r16];
    double lsum = 0.0;
    #pragma unroll
    for (int h = 0; h < 4; ++h) {
      const int d = d0 + h * 4;
      const float4 ev = *(const float4*)(cb + (size_t)codeB * DIMD + d);
      const float4 rv = *(const float4*)&residF[r16][d];
      float t0 = __fsub_rn(ev.x, rv.x), u0 = __fadd_rn(rv.x, t0);
      float t1 = __fsub_rn(ev.y, rv.y), u1 = __fadd_rn(rv.y, t1);
      float t2 = __fsub_rn(ev.z, rv.z), u2 = __fadd_rn(rv.z, t2);
      float t3 = __fsub_rn(ev.w, rv.w), u3 = __fadd_rn(rv.w, t3);
      *(float4*)&residF[r16][d] =
          make_float4(__fsub_rn(rv.x, u0), __fsub_rn(rv.y, u1),
                      __fsub_rn(rv.z, u2), __fsub_rn(rv.w, u3));
      lsum += (double)__fmul_rn(t0, t0) + (double)__fmul_rn(t1, t1) +
              (double)__fmul_rn(t2, t2) + (double)__fmul_rn(t3, t3);
    }
    #pragma unroll
    for (int off = 32; off; off >>= 1) lsum += __shfl_xor(lsum, off, 64);
    if (lane == 0) lossW[wv] = lsum;
    __syncthreads();   // also orders residF writes before next stage's reads
    if (tid == 0) {
      double s = 0.0;
      #pragma unroll
      for (int w = 0; w < NW; ++w) s += lossW[w];
      atomicAdd(lossP + (size_t)qi * 64 + (blockIdx.x & 63), s);
    }
  }

  // epilogue: out_q = fl(x - resid_final)
  {
    const float* xp = x + (size_t)(rowBase + r16) * DIMD + d0;
    float* op = out_q + (size_t)(rowBase + r16) * DIMD + d0;
    #pragma unroll
    for (int h = 0; h < 4; ++h) {
      const float4 a = *(const float4*)(xp + h * 4);
      const float4 b = *(const float4*)&residF[r16][d0 + h * 4];
      *(float4*)(op + h * 4) =
          make_float4(__fsub_rn(a.x, b.x), __fsub_rn(a.y, b.y),
                      __fsub_rn(a.z, b.z), __fsub_rn(a.w, b.w));
    }
  }

  // folded k_loss: last block to finish sums lossP (device-scope atomics
  // both sides; __threadfence orders this block's lossP adds first).
  __syncthreads();
  if (tid == 0) {
    __threadfence();
    unsigned old = atomicAdd(doneCnt, 1u);
    cnt[0] = (old == (unsigned)(gridDim.x - 1)) ? 1 : 0;
  }
  __syncthreads();
  if (cnt[0] && tid < 64) {
    const int qi2 = tid >> 4;
    double s = 0.0;
    #pragma unroll
    for (int i = 0; i < 4; ++i)
      s += atomicAdd(lossP + (size_t)qi2 * 64 + (tid & 15) * 4 + i, 0.0);
    #pragma unroll
    for (int off = 8; off; off >>= 1) s += __shfl_down(s, off, 16);
    if ((tid & 15) == 0)
      out_loss[qi2] = (float)(s * (1.0 / (double)((size_t)MM * DIMD)));
  }
}

extern "C" void kernel_launch(void* const* d_in, const int* in_sizes, int n_in,
                              void* d_out, int out_size, void* d_ws, size_t ws_size,
                              hipStream_t stream) {
  const float* x = (const float*)d_in[0];        // [8,2048,256]
  const float* cb = (const float*)d_in[1];       // [4,1024,256]
  float* ws = (float*)d_ws;
  unsigned short* cbT = (unsigned short*)ws;     // 1,048,576 ushort (transposed)
  float* bK = ws + 524288;
  double* lossP = (double*)(ws + 528384);        // [QQ][64], byte off %8==0
  unsigned* done = (unsigned*)(ws + 528896);

  float* out = (float*)d_out;
  float* out_idx = out + (size_t)MM * DIMD;      // 4,194,304
  float* out_loss = out_idx + (size_t)QQ * MM;   // +65,536

  k_prep<<<dim3(QQ * NE / 8), dim3(256), 0, stream>>>(cb, cbT, bK, lossP, done);
  k_fused<<<dim3(MM / TM), dim3(512), 0, stream>>>(x, cbT, cb, bK, lossP,
                                                   done, out, out_idx, out_loss);
}